// Round 9
// baseline (667.837 us; speedup 1.0000x reference)
//
#include <hip/hip_runtime.h>
#include <hip/hip_bf16.h>
#include <math.h>

// Shapes: BSZ=64, A_NUM=2, N_LAYER=4, DIM0=64, DIM1=256, SD0=SD1=64, K_OUT=8, UPS=4
// R8->R9: k2 rewritten: 8 rows/thread (32 FMA per ds_read, 8 indep chains), both
// j-branches fused per block (sX staged once, E in separate sE), grid 256x512thr.
// Conv section: k5b/k8_res eliminated - residual+scale fused into conv1/k9 tap reads,
// x ping-pong between xmag region and d_out-as-scratch. 29 kernels total.

// ---------------- K0: combined input weights + C init ----------------
__global__ void k0_prep(const float* __restrict__ Wr, const float* __restrict__ Wi,
                        const float* __restrict__ pr, const float* __restrict__ pi,
                        float* __restrict__ ArT, float* __restrict__ AiT,
                        float2* __restrict__ C) {
    int w  = blockIdx.x;    // 0..63   (SD1)
    int w2 = threadIdx.x;   // 0..255  (DIM1)
    float p0r = pr[0], p1r = pr[1], p0i = pi[0], p1i = pi[1];
    float wr0 = Wr[w2 * 64 + w],         wi0 = Wi[w2 * 64 + w];
    float wr1 = Wr[(256 + w2) * 64 + w], wi1 = Wi[(256 + w2) * 64 + w];
    ArT[w * 256 + w2] = p0r * wr0 - p0i * wi0 + p1r * wr1 - p1i * wi1;
    AiT[w * 256 + w2] = p0r * wi0 + p0i * wr0 + p1r * wi1 + p1i * wr1;
    if (w2 < 64) C[w * 64 + w2] = make_float2(1.f, 0.f);  // blockIdx.x = b here
}

// ---------------- K0b: transpose the 8 branch matrices ----------------
__global__ void k0b_T(const float* __restrict__ Wmr, const float* __restrict__ Wmi,
                      float* __restrict__ WmrT, float* __restrict__ WmiT) {
    int m = blockIdx.x;   // 0..7
    int t = threadIdx.x;  // 256
    const float* sr = Wmr + m * 4096;
    const float* si = Wmi + m * 4096;
    float* dr = WmrT + m * 4096;
    float* di = WmiT + m * 4096;
    for (int k = t; k < 4096; k += 256) {
        int c = k >> 6, h = k & 63;
        dr[h * 64 + c] = sr[k];
        di[h * 64 + c] = si[k];
    }
}

// ---------------- K1: G[b,h,w2] = sum_w x[b,h,w] * A[w2,w] (complex) ----------------
__global__ __launch_bounds__(256) void k1_G(const float* __restrict__ inp,
                                            const float* __restrict__ ArT,
                                            const float* __restrict__ AiT,
                                            float* __restrict__ Gr, float* __restrict__ Gi) {
    int hc = blockIdx.x;   // 8 row-chunks of 8
    int b  = blockIdx.y;
    int t  = threadIdx.x;  // w2
    __shared__ float sxr[8][64], sxi[8][64];
    int base_r = (b * 2 + 0) * 4096 + hc * 8 * 64;
    int base_i = (b * 2 + 1) * 4096 + hc * 8 * 64;
    for (int k = t; k < 512; k += 256) {
        int r = k >> 6, w = k & 63;
        sxr[r][w] = inp[base_r + r * 64 + w];
        sxi[r][w] = inp[base_i + r * 64 + w];
    }
    __syncthreads();
    float accr[8], acci[8];
#pragma unroll
    for (int r = 0; r < 8; r++) { accr[r] = 0.f; acci[r] = 0.f; }
    for (int k = 0; k < 64; k++) {
        float ar = ArT[k * 256 + t], ai = AiT[k * 256 + t];
#pragma unroll
        for (int r = 0; r < 8; r++) {
            float xr = sxr[r][k], xi = sxi[r][k];
            accr[r] += xr * ar - xi * ai;
            acci[r] += xi * ar + xr * ai;
        }
    }
#pragma unroll
    for (int r = 0; r < 8; r++) {
        int h = hc * 8 + r;
        Gr[(b * 64 + h) * 256 + t] = accr[r];
        Gi[(b * 64 + h) * 256 + t] = acci[r];
    }
}

// ---------------- K2: both branches of one layer, 8 rows/thread ----------------
__global__ __launch_bounds__(512) void k2_layer(const float* __restrict__ Gr,
                                                const float* __restrict__ Gi,
                                                const float2* __restrict__ C,
                                                const float* __restrict__ Wmr,
                                                const float* __restrict__ Wmi,
                                                const float* __restrict__ WmrT,
                                                const float* __restrict__ WmiT,
                                                float2* __restrict__ wsum, int layer) {
    int wc = blockIdx.x;  // 4 column chunks of 64
    int b  = blockIdx.y;  // 64
    int t = threadIdx.x, tx = t & 63, ty = t >> 6;  // ty 0..7
    __shared__ float2 sX[4096];  // [h][w]  C*G, stable across both branches
    __shared__ float2 sE[4096];  // [c][w]  E, rebuilt per branch
    int h0 = __builtin_amdgcn_readfirstlane(ty << 3);  // wave-uniform row base

    int gbase = b * 16384 + wc * 64 + tx;
    float gr_[8], gi_[8];
#pragma unroll
    for (int r = 0; r < 8; r++) {
        int h = h0 + r;
        float gr = Gr[gbase + h * 256], gi = Gi[gbase + h * 256];
        gr_[r] = gr; gi_[r] = gi;
        float2 c = C[b * 64 + h];
        sX[h * 64 + tx] = make_float2(c.x * gr - c.y * gi, c.x * gi + c.y * gr);
    }
    __syncthreads();

    for (int j = 0; j < 2; j++) {
        int mat = layer + 4 * j;
        const float* Wr0  = Wmr  + mat * 4096 + h0 * 64;  // I: rows c0.., contiguous in h
        const float* Wi0  = Wmi  + mat * 4096 + h0 * 64;
        const float* WrT0 = WmrT + mat * 4096 + h0 * 64;  // Z: rows h0.., contiguous in c
        const float* WiT0 = WmiT + mat * 4096 + h0 * 64;

        // I[c][tx], c = h0+r : 1 ds_read_b64 feeds 32 FMA over 8 indep chains
        float Ir[8] = {0,0,0,0,0,0,0,0}, Ii[8] = {0,0,0,0,0,0,0,0};
#pragma unroll 4
        for (int h = 0; h < 64; h++) {
            float2 x = sX[h * 64 + tx];
#pragma unroll
            for (int r = 0; r < 8; r++) {
                float wr = Wr0[r * 64 + h], wi = Wi0[r * 64 + h];
                Ir[r] += wr * x.x - wi * x.y;
                Ii[r] += wr * x.y + wi * x.x;
            }
        }
        // E = (1+log|I|^2) * conj(I)
#pragma unroll
        for (int r = 0; r < 8; r++) {
            float m2 = Ir[r] * Ir[r] + Ii[r] * Ii[r];
            float s = 1.f + __logf(m2);
            sE[(h0 + r) * 64 + tx] = make_float2(s * Ir[r], -s * Ii[r]);
        }
        __syncthreads();

        // Z[h][tx], h = h0+r
        float Zr[8] = {0,0,0,0,0,0,0,0}, Zi[8] = {0,0,0,0,0,0,0,0};
#pragma unroll 4
        for (int c = 0; c < 64; c++) {
            float2 e = sE[c * 64 + tx];
#pragma unroll
            for (int r = 0; r < 8; r++) {
                float wr = WrT0[r * 64 + c], wi = WiT0[r * 64 + c];
                Zr[r] += wr * e.x - wi * e.y;
                Zi[r] += wr * e.y + wi * e.x;
            }
        }
        // partial w-sum over this 64-column chunk
#pragma unroll
        for (int r = 0; r < 8; r++) {
            int h = h0 + r;
            float pr = gr_[r] * Zr[r] - gi_[r] * Zi[r];
            float pi = gr_[r] * Zi[r] + gi_[r] * Zr[r];
#pragma unroll
            for (int off = 32; off > 0; off >>= 1) {
                pr += __shfl_xor(pr, off);
                pi += __shfl_xor(pi, off);
            }
            if (tx == 0) wsum[((b * 64 + h) * 2 + j) * 4 + wc] = make_float2(pr, pi);
        }
        __syncthreads();  // sE reuse fence for next branch
    }
}

// ---------------- K3: C update ----------------
__global__ void k3_cupdate(const float2* __restrict__ wsum, float2* __restrict__ C,
                           const float* __restrict__ Wcr, const float* __restrict__ Wci,
                           int layer) {
    int id = blockIdx.x * 256 + threadIdx.x;  // (b*64+h), 4096 total
    float accr = 0.f, acci = 0.f;
#pragma unroll
    for (int j = 0; j < 2; j++) {
        float wr = 0.f, wi = 0.f;
#pragma unroll
        for (int wc = 0; wc < 4; wc++) {
            float2 p = wsum[(id * 2 + j) * 4 + wc];
            wr += p.x; wi += p.y;
        }
        float m2 = wr * wr + wi * wi;
        float cr, ci;
        if (m2 > 0.f) {
            float inv = 1.f / sqrtf(m2);
            cr = wr * inv; ci = -wi * inv;   // cos(atan2), -sin(atan2)
        } else { cr = 1.f; ci = 0.f; }
        float wcr = Wcr[layer * 2 + j], wci = Wci[layer * 2 + j];
        accr += cr * wcr - ci * wci;
        acci += ci * wcr + cr * wci;
    }
    C[id] = make_float2(accr, acci);
}

// ---------------- K4: final projection |W_l3 · (C⊙G)| + block max ----------------
__global__ __launch_bounds__(1024) void k4_proj(const float* __restrict__ Gr,
                                                const float* __restrict__ Gi,
                                                const float2* __restrict__ C,
                                                const float* __restrict__ W3r,
                                                const float* __restrict__ W3i,
                                                float* __restrict__ xmag,
                                                float* __restrict__ pmax) {
    int wc = blockIdx.x;   // 4 col chunks
    int cb = blockIdx.y;   // 2 c-halves of 64
    int b  = blockIdx.z;
    int t = threadIdx.x, tx = t & 63, ty = t >> 6;  // ty 0..15
    __shared__ float2 sX[4096];
    int c0 = __builtin_amdgcn_readfirstlane(ty << 2);
    const float* W3r0 = W3r + (cb * 64 + c0) * 64;
    const float* W3i0 = W3i + (cb * 64 + c0) * 64;
    int gbase = b * 16384 + wc * 64 + tx;
#pragma unroll
    for (int r = 0; r < 4; r++) {
        int h = (ty << 2) + r;
        float gr = Gr[gbase + h * 256], gi = Gi[gbase + h * 256];
        float2 c = C[b * 64 + h];
        sX[h * 64 + tx] = make_float2(c.x * gr - c.y * gi, c.x * gi + c.y * gr);
    }
    __syncthreads();
    float Fr[4] = {0,0,0,0}, Fi[4] = {0,0,0,0};
#pragma unroll 8
    for (int h = 0; h < 64; h++) {
        float2 x = sX[h * 64 + tx];
#pragma unroll
        for (int r = 0; r < 4; r++) {
            float wr = W3r0[r * 64 + h], wi = W3i0[r * 64 + h];
            Fr[r] += wr * x.x - wi * x.y;
            Fi[r] += wr * x.y + wi * x.x;
        }
    }
    float mx = 0.f;
#pragma unroll
    for (int r = 0; r < 4; r++) {
        int cl = (ty << 2) + r;
        float mag = sqrtf(Fr[r] * Fr[r] + Fi[r] * Fi[r]);
        xmag[(b * 128 + cb * 64 + cl) * 256 + wc * 64 + tx] = mag;
        mx = fmaxf(mx, mag);
    }
#pragma unroll
    for (int off = 32; off > 0; off >>= 1) mx = fmaxf(mx, __shfl_xor(mx, off));
    __syncthreads();
    float* scratch = (float*)sX;
    if (tx == 0) scratch[ty] = mx;
    __syncthreads();
    if (t == 0) {
        float m = scratch[0];
#pragma unroll
        for (int k = 1; k < 16; k++) m = fmaxf(m, scratch[k]);
        pmax[b * 8 + cb * 4 + wc] = m;
    }
}

// ---------------- conv1 fused: input tap = scale(x) [L0] or relu(x + bn2(h2)) [L1-3] ----
// Also materializes x_i (this layer's input) at center taps into xout.
__global__ __launch_bounds__(256) void k_conv1f(const float* __restrict__ xin,
                                                const float* __restrict__ h2,
                                                const float* __restrict__ cw,
                                                const float* __restrict__ stats2,
                                                const float* __restrict__ pmax,
                                                float* __restrict__ hout,
                                                float* __restrict__ xout,
                                                float* __restrict__ psum,
                                                float* __restrict__ psumsq,
                                                int layer) {
    int hb = blockIdx.x;  // 16 row chunks of 4
    int co = blockIdx.y;  // 2
    int b  = blockIdx.z;
    int tx = threadIdx.x;  // column 0..255
    float wgt[18];
    const float* wp = cw + layer * 36 + co * 18;
#pragma unroll
    for (int k = 0; k < 18; k++) wgt[k] = wp[k];
    float sc0 = 0.f, sc1 = 0.f, sh0 = 0.f, sh1 = 0.f, inv = 1.f;
    if (layer == 0) {
        float m = 0.f;
#pragma unroll
        for (int k = 0; k < 8; k++) m = fmaxf(m, pmax[b * 8 + k]);
        inv = 1.f / m;
    } else {
        sc0 = stats2[0]; sc1 = stats2[1]; sh0 = stats2[2]; sh1 = stats2[3];
    }
    int wm = (tx + 255) & 255, wpp = (tx + 1) & 255;
    float lsum = 0.f, lsq = 0.f;
    for (int r = 0; r < 4; r++) {
        int hh = hb * 4 + r;
        int hm = (hh + 63) & 63, hp = (hh + 1) & 63;
        const int rows[3] = {hm, hh, hp};
        const int cols[3] = {wm, tx, wpp};
        float acc = 0.f;
#pragma unroll
        for (int ci = 0; ci < 2; ci++) {
            const float* xp  = xin + (b * 2 + ci) * 16384;
            const float* hp2 = h2  + (b * 2 + ci) * 16384;
            float sc = ci ? sc1 : sc0, sh = ci ? sh1 : sh0;
            const float* wg = wgt + ci * 9;
#pragma unroll
            for (int kh = 0; kh < 3; kh++)
#pragma unroll
                for (int kw = 0; kw < 3; kw++) {
                    int idx = rows[kh] * 256 + cols[kw];
                    float v;
                    if (layer == 0) v = xp[idx] * inv;
                    else            v = fmaxf(xp[idx] + hp2[idx] * sc + sh, 0.f);
                    if (ci == co && kh == 1 && kw == 1)
                        xout[(b * 2 + co) * 16384 + hh * 256 + tx] = v;
                    acc += wg[kh * 3 + kw] * v;
                }
        }
        hout[((b * 2 + co) * 64 + hh) * 256 + tx] = acc;
        lsum += acc; lsq += acc * acc;
    }
#pragma unroll
    for (int off = 32; off > 0; off >>= 1) {
        lsum += __shfl_xor(lsum, off);
        lsq  += __shfl_xor(lsq, off);
    }
    __shared__ float ssum[4], ssq[4];
    int tyy = tx >> 6, lane = tx & 63;
    if (lane == 0) { ssum[tyy] = lsum; ssq[tyy] = lsq; }
    __syncthreads();
    if (tx == 0) {
        int bl = b * 16 + hb;
        psum[co * 1024 + bl]   = ssum[0] + ssum[1] + ssum[2] + ssum[3];
        psumsq[co * 1024 + bl] = ssq[0] + ssq[1] + ssq[2] + ssq[3];
    }
}

// ---------------- conv2: bn1+relu applied to input taps ----------------
__global__ __launch_bounds__(256) void k_conv2(const float* __restrict__ h1,
                                               const float* __restrict__ cw,
                                               const float* __restrict__ stats1,
                                               float* __restrict__ hout,
                                               float* __restrict__ psum,
                                               float* __restrict__ psumsq,
                                               int layer) {
    int hb = blockIdx.x;  // 16 row chunks of 4
    int co = blockIdx.y;  // 2
    int b  = blockIdx.z;
    int tx = threadIdx.x;
    float wgt[18];
    const float* wp = cw + layer * 36 + co * 18;
#pragma unroll
    for (int k = 0; k < 18; k++) wgt[k] = wp[k];
    float sc0 = stats1[0], sc1 = stats1[1], sh0 = stats1[2], sh1 = stats1[3];
    int wm = (tx + 255) & 255, wpp = (tx + 1) & 255;
    float lsum = 0.f, lsq = 0.f;
    for (int r = 0; r < 4; r++) {
        int hh = hb * 4 + r;
        int hm = (hh + 63) & 63, hp = (hh + 1) & 63;
        const int rows[3] = {hm, hh, hp};
        const int cols[3] = {wm, tx, wpp};
        float acc = 0.f;
#pragma unroll
        for (int ci = 0; ci < 2; ci++) {
            const float* xp = h1 + (b * 2 + ci) * 16384;
            float sc = ci ? sc1 : sc0, sh = ci ? sh1 : sh0;
            const float* wg = wgt + ci * 9;
#pragma unroll
            for (int kh = 0; kh < 3; kh++)
#pragma unroll
                for (int kw = 0; kw < 3; kw++) {
                    float v = fmaxf(xp[rows[kh] * 256 + cols[kw]] * sc + sh, 0.f);
                    acc += wg[kh * 3 + kw] * v;
                }
        }
        hout[((b * 2 + co) * 64 + hh) * 256 + tx] = acc;
        lsum += acc; lsq += acc * acc;
    }
#pragma unroll
    for (int off = 32; off > 0; off >>= 1) {
        lsum += __shfl_xor(lsum, off);
        lsq  += __shfl_xor(lsq, off);
    }
    __shared__ float ssum[4], ssq[4];
    int tyy = tx >> 6, lane = tx & 63;
    if (lane == 0) { ssum[tyy] = lsum; ssq[tyy] = lsq; }
    __syncthreads();
    if (tx == 0) {
        int bl = b * 16 + hb;
        psum[co * 1024 + bl]   = ssum[0] + ssum[1] + ssum[2] + ssum[3];
        psumsq[co * 1024 + bl] = ssq[0] + ssq[1] + ssq[2] + ssq[3];
    }
}

// ---------------- stats finalize -> scale/shift ----------------
__global__ void k_stats(const float* __restrict__ psum, const float* __restrict__ psumsq,
                        const float* __restrict__ g, const float* __restrict__ bb,
                        float* __restrict__ stats, int layer) {
    int ch = threadIdx.x >> 6, lane = threadIdx.x & 63;  // 128 threads
    float s = 0.f, q = 0.f;
    for (int k = lane; k < 1024; k += 64) { s += psum[ch * 1024 + k]; q += psumsq[ch * 1024 + k]; }
#pragma unroll
    for (int off = 32; off > 0; off >>= 1) { s += __shfl_xor(s, off); q += __shfl_xor(q, off); }
    if (lane == 0) {
        const float N = 1048576.f;
        float mu = s / N;
        float var = q / N - mu * mu;
        float rs = rsqrtf(var + 1e-5f);
        float gamma = g[layer * 2 + ch];
        stats[ch]     = rs * gamma;
        stats[2 + ch] = bb[layer * 2 + ch] - mu * rs * gamma;
    }
}

// ---------------- K9: transposed conv; final residual applied on the fly ----------------
__global__ void k9_out(const float* __restrict__ x3, const float* __restrict__ h2,
                       const float* __restrict__ stats2, const float* __restrict__ Wout,
                       float* __restrict__ out) {
    const int TOT = 64 * 257 * 1025;
    int id = blockIdx.x * 256 + threadIdx.x;
    if (id >= TOT) return;
    int b   = id / 263425;
    int rem = id - b * 263425;
    int oh  = rem / 1025;
    int ow  = rem - oh * 1025;
    int kh0 = (5 - oh) & 3;
    int kw0 = (5 - ow) & 3;
    float sc0 = stats2[0], sc1 = stats2[1], sh0 = stats2[2], sh1 = stats2[3];
    float acc = 0.f;
#pragma unroll
    for (int ah = 0; ah < 2; ah++) {
        int kh = kh0 + 4 * ah;
        int d = oh + kh - 5;
        if (d < 0 || d > 252) continue;
        int rh = d >> 2;
#pragma unroll
        for (int aw = 0; aw < 2; aw++) {
            int kw = kw0 + 4 * aw;
            int e = ow + kw - 5;
            if (e < 0 || e > 1020) continue;
            int rw = e >> 2;
#pragma unroll
            for (int ci = 0; ci < 2; ci++) {
                int idx = ((b * 2 + ci) * 64 + rh) * 256 + rw;
                float v = fmaxf(x3[idx] + h2[idx] * (ci ? sc1 : sc0) + (ci ? sh1 : sh0), 0.f);
                float wv = Wout[ci * 64 + (7 - kh) * 8 + (7 - kw)];
                acc += wv * v;
            }
        }
    }
    out[id] = acc;
}

extern "C" void kernel_launch(void* const* d_in, const int* in_sizes, int n_in,
                              void* d_out, int out_size, void* d_ws, size_t ws_size,
                              hipStream_t stream) {
    const float* inp   = (const float*)d_in[0];
    const float* Winr  = (const float*)d_in[1];
    const float* Wini  = (const float*)d_in[2];
    const float* Wprer = (const float*)d_in[3];
    const float* Wprei = (const float*)d_in[4];
    const float* Wmr   = (const float*)d_in[5];
    const float* Wmi   = (const float*)d_in[6];
    const float* Wcr   = (const float*)d_in[7];
    const float* Wci   = (const float*)d_in[8];
    const float* W3r   = (const float*)d_in[9];
    const float* W3i   = (const float*)d_in[10];
    const float* cw1   = (const float*)d_in[11];
    const float* bn1g  = (const float*)d_in[12];
    const float* bn1b  = (const float*)d_in[13];
    const float* cw2   = (const float*)d_in[14];
    const float* bn2g  = (const float*)d_in[15];
    const float* bn2b  = (const float*)d_in[16];
    const float* Wout  = (const float*)d_in[17];
    float* out = (float*)d_out;

    float* ws = (float*)d_ws;
    float*  ArT   = ws;                         // 16384
    float*  AiT   = ArT + 16384;                // 16384
    float2* C     = (float2*)(AiT + 16384);     // 4096 f2
    float*  Gr    = (float*)C + 8192;           // 1048576
    float*  Gi    = Gr + 1048576;               // 1048576
    float2* wsum  = (float2*)(Gi + 1048576);    // 32768 f2
    float*  xmag  = (float*)wsum + 65536;       // 2097152
    float*  h2    = xmag + 2097152;             // 2097152
    float*  pmax  = h2 + 2097152;               // 512
    float*  psum1 = pmax + 512;                 // 2048
    float*  psq1  = psum1 + 2048;               // 2048
    float*  psum2 = psq1 + 2048;                // 2048
    float*  psq2  = psum2 + 2048;               // 2048
    float*  stats = psq2 + 2048;                // 8 (bn1: 0..3, bn2: 4..7)
    float*  h1    = Gr;   // overlay: Gr+Gi dead after k4_proj (2.1M floats)
    float*  WmrT  = h2;   // overlay: WT lifetime ends before conv section writes h2
    float*  WmiT  = h2 + 32768;
    float*  outS  = out;  // d_out as 8MB scratch until k9 writes it

    k0_prep<<<64, 256, 0, stream>>>(Winr, Wini, Wprer, Wprei, ArT, AiT, C);
    k0b_T<<<8, 256, 0, stream>>>(Wmr, Wmi, WmrT, WmiT);
    k1_G<<<dim3(8, 64), 256, 0, stream>>>(inp, ArT, AiT, Gr, Gi);
    for (int i = 0; i < 4; i++) {
        k2_layer<<<dim3(4, 64), 512, 0, stream>>>(Gr, Gi, C, Wmr, Wmi, WmrT, WmiT, wsum, i);
        k3_cupdate<<<16, 256, 0, stream>>>(wsum, C, Wcr, Wci, i);
    }
    k4_proj<<<dim3(4, 2, 64), 1024, 0, stream>>>(Gr, Gi, C, W3r, W3i, xmag, pmax);

    // conv section: x ping-pong  x0=outS, x1=xmag, x2=outS, x3=xmag
    float* xbuf[5] = {xmag, outS, xmag, outS, xmag};  // xbuf[i]=input of layer i's conv1 (i>=1: materialized x_{i})
    for (int i = 0; i < 4; i++) {
        const float* xin = xbuf[i];       // layer0: raw xmag; else materialized x_{i-1}... (see below)
        float* xout = xbuf[i + 1];
        k_conv1f<<<dim3(16, 2, 64), 256, 0, stream>>>(xin, h2, cw1, stats + 4, pmax,
                                                      h1, xout, psum1, psq1, i);
        k_stats<<<1, 128, 0, stream>>>(psum1, psq1, bn1g, bn1b, stats, i);
        k_conv2<<<dim3(16, 2, 64), 256, 0, stream>>>(h1, cw2, stats, h2, psum2, psq2, i);
        k_stats<<<1, 128, 0, stream>>>(psum2, psq2, bn2g, bn2b, stats + 4, i);
    }
    // xbuf[4] = xmag holds x3 (input of the final residual); k9 applies relu(x3+bn2(h2))
    k9_out<<<65857, 256, 0, stream>>>(xmag, h2, stats + 4, Wout, out);
}